// Round 14
// baseline (46.657 us; speedup 1.0000x reference)
//
#include <hip/hip_runtime.h>
#include <math.h>

// E8S codebook quantization via 32x32x16 bf16 MFMA pairs, exact 3-way split.
//   scores[r][c] = 2*X[r]·G[c] - ||G[c]||^2 ; idx = first-argmax over c.
// Exactness: G coords multiples of 0.25 (exact bf16); 2*X = h+m+l exact
// 3-term bf16 split; gn multiple of 0.5 < 16 (exact bf16, folded into K as
// gn * -1).  Tile = 32 codewords x 32 rows, kg = lane>>5:
//   stage1: A=coords, B=(kg? m : h)                   -> (h+m)·g
//   stage2: A=(kg? [gn,0..] : coords), B=(kg? [-1,0..] : l), C=stage1
// D layout: col=lane&31 (X row), cw_in_tile=(reg&3)+8*(reg>>2)+4*kg.
// R13: G tiles staged through LDS once per block (R10-R12 were L2-BW bound:
// 2KB/wave-step from L2 = 438 cyc/SIMD-round > 384 cyc MFMA issue, with all
// 4 waves re-reading identical data). Tile-major Gb layout [tile][coord-half|
// gn-half] gives conflict-free 16B-stride ds_read_b128. 16-tile batches,
// double-buffered, T14 async stage split (load early / ds_write late).
// R14: uint4 -> native ext_vector u32x4 (HIP uint4 is struct-backed; "+v"
// tied constraint on it doesn't compile: "tied indirect register inputs").
// dE/dO accumulator rotation (R12) keeps MFMA issue overlapped with the
// max-tree. Resolve re-runs the winning tile bit-identically (np.argmax
// first-max semantics).

typedef short short8 __attribute__((ext_vector_type(8)));
typedef float f32x16 __attribute__((ext_vector_type(16)));
typedef unsigned int u32x4 __attribute__((ext_vector_type(4)));

constexpr int NROWS  = 8192;
constexpr int NCW    = 55650;
constexpr int NT     = 1740;          // 32-codeword tiles
constexpr int NCWP   = NT * 32;       // 55680
constexpr int NCHUNK = 24;            // tile chunks (grid.y)
constexpr int RBLK   = 32;            // row blocks of 256 rows (grid.x)
constexpr int NB     = 16;            // tiles per LDS batch (16 KB)

// workspace layout (bytes)
// Gb: [NT][1024B]: bytes [0,512) = 32 cw x 8 bf16 coords; [512,1024) =
//     32 cw x [gn,0,0,0,0,0,0,0] bf16.
constexpr size_t OFF_GB = 0;
constexpr size_t OFF_XS = OFF_GB + (size_t)NT * 1024;   // ushort Xs[NROWS*4*8]
constexpr size_t OFF_BK = OFF_XS + (size_t)NROWS * 64;  // u64 best[NROWS]

__device__ inline unsigned short bf16_rne(float f) {
  unsigned int u = __float_as_uint(f);
  unsigned int r = u + 0x7FFFu + ((u >> 16) & 1u);
  return (unsigned short)(r >> 16);
}
__device__ inline float bf16_f(unsigned short h) {
  return __uint_as_float(((unsigned int)h) << 16);
}
__device__ inline unsigned int enc_ord(float f) {
  unsigned int u = __float_as_uint(f);
  return (u & 0x80000000u) ? ~u : (u | 0x80000000u);
}
__device__ inline float dec_ord(unsigned int e) {
  unsigned int u = (e & 0x80000000u) ? (e & 0x7FFFFFFFu) : ~e;
  return __uint_as_float(u);
}
__device__ inline float max16(const f32x16& d) {
  float t1 = fmaxf(fmaxf(d[0], d[1]), d[2]);
  float t2 = fmaxf(fmaxf(d[3], d[4]), d[5]);
  float t3 = fmaxf(fmaxf(d[6], d[7]), d[8]);
  float t4 = fmaxf(fmaxf(d[9], d[10]), d[11]);
  float t5 = fmaxf(fmaxf(d[12], d[13]), d[14]);
  float u1 = fmaxf(fmaxf(t1, t2), t3);
  float u2 = fmaxf(fmaxf(t4, t5), d[15]);
  return fmaxf(u1, u2);
}

__global__ __launch_bounds__(256) void e8_prep(
    const float* __restrict__ X, const float* __restrict__ G,
    const float* __restrict__ GN, unsigned char* __restrict__ GbB,
    unsigned short* __restrict__ Xs, unsigned long long* __restrict__ best) {
  int i = blockIdx.x * 256 + threadIdx.x;
  if (i < NCWP) {
    unsigned short c8[8], n8[8];
    if (i < NCW) {
      for (int j = 0; j < 8; ++j) c8[j] = bf16_rne(G[(size_t)i*8+j]);
      n8[0] = bf16_rne(GN[i]);          // exact: multiple of 0.5, < 16
      for (int j = 1; j < 8; ++j) n8[j] = 0;
    } else {
      for (int j = 0; j < 8; ++j) c8[j] = 0;
      n8[0] = 0x7F7F;                   // bf16 max finite -> score ~ -3.4e38
      for (int j = 1; j < 8; ++j) n8[j] = 0;
    }
    unsigned char* base = GbB + (size_t)(i >> 5) * 1024 + (size_t)(i & 31) * 16;
    *reinterpret_cast<u32x4*>(base)       = *reinterpret_cast<u32x4*>(c8);
    *reinterpret_cast<u32x4*>(base + 512) = *reinterpret_cast<u32x4*>(n8);
  } else if (i < NCWP + NROWS) {
    int r = i - NCWP;
    unsigned short hh[8], mm[8], ll[8], qq[8];
    for (int j = 0; j < 8; ++j) {
      float s = 2.0f * X[(size_t)r*8+j];           // exact
      unsigned short h = bf16_rne(s);  float r1 = s  - bf16_f(h);  // exact
      unsigned short m = bf16_rne(r1); float r2 = r1 - bf16_f(m);  // exact
      unsigned short l = bf16_rne(r2);             // residual after 3 terms = 0
      hh[j] = h; mm[j] = m; ll[j] = l;
      qq[j] = (j == 0) ? (unsigned short)0xBF80 : 0;  // -1.0
    }
    u32x4* dst = reinterpret_cast<u32x4*>(Xs + (size_t)r * 32);
    dst[0] = *reinterpret_cast<u32x4*>(hh);
    dst[1] = *reinterpret_cast<u32x4*>(mm);
    dst[2] = *reinterpret_cast<u32x4*>(ll);
    dst[3] = *reinterpret_cast<u32x4*>(qq);
    best[r] = 0ull;
  }
}

#define E8_ASM(D0, D1, A1, A2)                                             \
  asm volatile(                                                            \
      "v_mfma_f32_32x32x16_bf16 %0, %2, %4, %8\n\t"                        \
      "v_mfma_f32_32x32x16_bf16 %1, %2, %5, %8\n\t"                        \
      "v_mfma_f32_32x32x16_bf16 %0, %3, %6, %0\n\t"                        \
      "v_mfma_f32_32x32x16_bf16 %1, %3, %7, %1\n\t"                        \
      "s_nop 7\n\t"                                                        \
      "s_nop 7"                                                            \
      : "=&v"(D0), "=&v"(D1)                                               \
      : "v"(A1), "v"(A2), "v"(b10), "v"(b11), "v"(b20), "v"(b21), "v"(cz))

#define E8_PIN(P0, P1, T0) asm("" : "+v"(P0), "+v"(P1) : "v"(T0))

#define E8_TRACK(D0, D1, TILE)                                             \
  {                                                                        \
    const float m0 = max16(D0);                                            \
    const float m1 = max16(D1);                                            \
    bi0 = (m0 > bs0) ? (TILE) : bi0;  bs0 = fmaxf(bs0, m0);                \
    bi1 = (m1 > bs1) ? (TILE) : bi1;  bs1 = fmaxf(bs1, m1);                \
  }

#define E8_LDSA(A1, A2, TL)                                                \
  A1 = *reinterpret_cast<const short8*>(lb + (TL) * 1024 + l31 * 16);      \
  A2 = *reinterpret_cast<const short8*>(lb + (TL) * 1024 + kgoff + l31 * 16);

// Per block: 4 waves x 2 row-tiles = 256 rows, chunk of 72-73 cw-tiles.
// Grid 32x24 = 768 blocks = 3 blocks/CU = 3 waves/SIMD. LDS 32 KB/block.
__global__ __launch_bounds__(256, 3) void e8_main(
    const unsigned char* __restrict__ GbB,
    const unsigned short* __restrict__ Xs,
    unsigned long long* __restrict__ best) {
  const int lane = threadIdx.x & 63;
  const int wave = threadIdx.x >> 6;
  const int kg = lane >> 5, l31 = lane & 31;
  const int kgoff = kg << 9;            // 0 or 512 bytes
  const int rowbase = blockIdx.x * 256 + wave * 64;

  __shared__ u32x4 smem4[2048];         // 32 KB: two 16-tile buffers
  unsigned char* smemB = reinterpret_cast<unsigned char*>(smem4);

  short8 b10, b11, b20, b21;
  {
    const size_t row0 = (size_t)rowbase + l31;
    const size_t row1 = row0 + 32;
    b10 = *reinterpret_cast<const short8*>(Xs + (row0*4 + kg)*8);
    b20 = *reinterpret_cast<const short8*>(Xs + (row0*4 + 2 + kg)*8);
    b11 = *reinterpret_cast<const short8*>(Xs + (row1*4 + kg)*8);
    b21 = *reinterpret_cast<const short8*>(Xs + (row1*4 + 2 + kg)*8);
  }
  asm("" : "+v"(b10), "+v"(b11), "+v"(b20), "+v"(b21));

  const int ct0 = blockIdx.y * NT / NCHUNK;
  const int ct1 = (blockIdx.y + 1) * NT / NCHUNK;

  f32x16 cz;
#pragma unroll
  for (int i = 0; i < 16; ++i) cz[i] = 0.0f;

  float bs0 = -INFINITY, bs1 = -INFINITY;
  int   bi0 = 0,         bi1 = 0;

  // ---- stage batch 0 ----
  {
    const int cnt0 = (ct1 - ct0 < NB) ? (ct1 - ct0) : NB;
#pragma unroll
    for (int t = 0; t < 4; ++t) {
      const int widx = wave * 4 + t;
      if (widx < cnt0) {
        u32x4 v = *reinterpret_cast<const u32x4*>(
            GbB + (size_t)(ct0 + widx) * 1024 + (size_t)lane * 16);
        *reinterpret_cast<u32x4*>(smemB + (size_t)widx * 1024 +
                                  (size_t)lane * 16) = v;
      }
    }
  }
  __syncthreads();

  int base = ct0, bufsel = 0;
  while (base < ct1) {
    const int cnt   = (ct1 - base < NB) ? (ct1 - base) : NB;
    const int nbase = base + cnt;
    const int ncnt  = (ct1 - nbase < NB) ? (ct1 - nbase) : NB;  // may be <=0

    // T14 async stage: issue next batch's global loads now, write after compute
    u32x4 sv0 = {0,0,0,0}, sv1 = {0,0,0,0}, sv2 = {0,0,0,0}, sv3 = {0,0,0,0};
#pragma unroll
    for (int t = 0; t < 4; ++t) {
      const int widx = wave * 4 + t;
      u32x4 v = {0, 0, 0, 0};
      if (widx < ncnt)
        v = *reinterpret_cast<const u32x4*>(
            GbB + (size_t)(nbase + widx) * 1024 + (size_t)lane * 16);
      if (t == 0) sv0 = v; else if (t == 1) sv1 = v;
      else if (t == 2) sv2 = v; else sv3 = v;
    }
    asm("" : "+v"(sv0), "+v"(sv1), "+v"(sv2), "+v"(sv3));

    // ---- compute cnt tiles from LDS buffer bufsel ----
    const unsigned char* lb = smemB + (size_t)bufsel * 16384;
    short8 aE1, aE2, aO1, aO2;
    f32x16 dE0, dE1, dO0, dO1;

    E8_LDSA(aE1, aE2, 0)
    if (cnt > 1) { E8_LDSA(aO1, aO2, 1) }
    E8_ASM(dE0, dE1, aE1, aE2);

    int i = 1;
    for (; i + 1 < cnt; i += 2) {
      {  // tile i (odd -> dO); preload i+1 into aE
        const int pt = i + 1;
        E8_LDSA(aE1, aE2, pt)
        E8_ASM(dO0, dO1, aO1, aO2);
        E8_PIN(dE0, dE1, dO0);
        E8_TRACK(dE0, dE1, base + i - 1)
      }
      {  // tile i+1 (even -> dE); preload i+2 into aO (clamped)
        const int pt = (i + 2 < cnt) ? i + 2 : 0;
        E8_LDSA(aO1, aO2, pt)
        E8_ASM(dE0, dE1, aE1, aE2);
        E8_PIN(dO0, dO1, dE0);
        E8_TRACK(dO0, dO1, base + i)
      }
    }
    if (i < cnt) {          // cnt even: last tile (odd index) still pending
      E8_ASM(dO0, dO1, aO1, aO2);
      E8_PIN(dE0, dE1, dO0);
      E8_TRACK(dE0, dE1, base + i - 1)
      E8_TRACK(dO0, dO1, base + i)
    } else {                // cnt odd: last tile was even -> dE
      E8_TRACK(dE0, dE1, base + cnt - 1)
    }

    // ---- write staged tiles, flip ----
#pragma unroll
    for (int t = 0; t < 4; ++t) {
      const int widx = wave * 4 + t;
      if (widx < ncnt) {
        const u32x4 v = (t == 0) ? sv0 : (t == 1) ? sv1 : (t == 2) ? sv2 : sv3;
        *reinterpret_cast<u32x4*>(smemB + (size_t)(bufsel ^ 1) * 16384 +
                                  (size_t)widx * 1024 + (size_t)lane * 16) = v;
      }
    }
    __syncthreads();
    bufsel ^= 1;
    base = nbase;
  }

  {
    unsigned long long key =
        ((unsigned long long)enc_ord(bs0) << 32) | (unsigned int)(~bi0);
    unsigned long long o = __shfl_xor(key, 32, 64);
    key = (o > key) ? o : key;
    if (lane < 32) atomicMax(&best[(size_t)rowbase + l31], key);
  }
  {
    unsigned long long key =
        ((unsigned long long)enc_ord(bs1) << 32) | (unsigned int)(~bi1);
    unsigned long long o = __shfl_xor(key, 32, 64);
    key = (o > key) ? o : key;
    if (lane < 32) atomicMax(&best[(size_t)rowbase + 32 + l31], key);
  }
}

// 256 blocks x 4 waves; wave handles 8 rows of its 32-row tile: re-run the
// bit-identical MFMA chain on each row's winning tile, smallest matching
// index, write vals + idx.
__global__ __launch_bounds__(256) void e8_resolve(
    const unsigned char* __restrict__ GbB,
    const unsigned short* __restrict__ Xs, const float* __restrict__ G,
    const unsigned long long* __restrict__ best, float* __restrict__ out) {
  const int lane = threadIdx.x & 63;
  const int wave = threadIdx.x >> 6;
  const int kg = lane >> 5, l31 = lane & 31;
  const int rt = blockIdx.x;              // 0..255

  short8 b1, b2;
  {
    const size_t row = (size_t)rt * 32 + l31;
    b1 = *reinterpret_cast<const short8*>(Xs + (row*4 + kg)*8);
    b2 = *reinterpret_cast<const short8*>(Xs + (row*4 + 2 + kg)*8);
  }
  f32x16 cz;
#pragma unroll
  for (int i = 0; i < 16; ++i) cz[i] = 0.0f;

  for (int j = wave * 8; j < wave * 8 + 8; ++j) {
    const int srow = rt * 32 + j;
    const unsigned long long k = best[srow];
    const float sstar = dec_ord((unsigned int)(k >> 32));
    const int twin = (int)(~(unsigned int)(k & 0xFFFFFFFFull));

    const unsigned char* ga = GbB + (size_t)twin * 1024 + (size_t)l31 * 16;
    short8 a1 = *reinterpret_cast<const short8*>(ga);
    short8 a2 = *reinterpret_cast<const short8*>(ga + (kg << 9));
    f32x16 d = __builtin_amdgcn_mfma_f32_32x32x16_bf16(a1, b1, cz, 0, 0, 0);
    d = __builtin_amdgcn_mfma_f32_32x32x16_bf16(a2, b2, d, 0, 0, 0);

    const int basei = twin * 32 + 4 * kg;
    int cand = 0x7FFFFFFF;
#pragma unroll
    for (int r = 15; r >= 0; --r)
      cand = (d[r] == sstar) ? (basei + ((r & 3) + 8 * (r >> 2))) : cand;
    if (l31 != j) cand = 0x7FFFFFFF;
    const int o = __shfl_xor(cand, 32, 64);
    cand = min(cand, o);
    if (lane == j) {
      const float4* g = reinterpret_cast<const float4*>(G + (size_t)cand * 8);
      float4 v0 = g[0], v1 = g[1];
      float4* od = reinterpret_cast<float4*>(out + (size_t)srow * 8);
      od[0] = v0; od[1] = v1;
      out[(size_t)NROWS * 8 + srow] = (float)(cand - 32768);
    }
  }
}

extern "C" void kernel_launch(void* const* d_in, const int* in_sizes, int n_in,
                              void* d_out, int out_size, void* d_ws, size_t ws_size,
                              hipStream_t stream) {
  const float* X  = (const float*)d_in[0];
  const float* G  = (const float*)d_in[1];
  const float* GN = (const float*)d_in[2];
  float* out = (float*)d_out;

  char* ws = (char*)d_ws;
  unsigned char*      GbB  = (unsigned char*)(ws + OFF_GB);
  unsigned short*     Xs   = (unsigned short*)(ws + OFF_XS);
  unsigned long long* best = (unsigned long long*)(ws + OFF_BK);

  e8_prep<<<(NCWP + NROWS + 255) / 256, 256, 0, stream>>>(X, G, GN, GbB, Xs, best);
  e8_main<<<dim3(RBLK, NCHUNK), 256, 0, stream>>>(GbB, Xs, best);
  e8_resolve<<<256, 256, 0, stream>>>(GbB, Xs, G, best, out);
}